// Round 19
// baseline (32.602 us; speedup 1.0000x reference)
//
#include <hip/hip_runtime.h>

// Problem constants (fixed by reference setup_inputs)
#define NB 32
#define NC 128
#define NH 63
#define NW 63
#define HW 3969          // 63*63
#define OH 30            // (63-5)/2+1
#define SEGW 15          // 15x15 block: 6 tiles x 6 strips, advance 12 in both dims
#define NROW 15
#define POSN (NROW*SEGW) // 225
#define NSST 5           // row superstrips per b (30 = 5*6)
#define NCS 5            // col segments per b (30 = 5*6)
#define NTIL 36          // tiles per block
#define NBLK (NB*NSST*NCS)  // 800
// 63 = 5*12 + 3 and 30 = 5*6 exactly -> no edge masking anywhere.

typedef _Float16 half2_t __attribute__((ext_vector_type(2)));
__device__ __forceinline__ half2_t u2h(unsigned u) { return __builtin_bit_cast(half2_t, u); }
__device__ __forceinline__ unsigned h2u(half2_t h) { return __builtin_bit_cast(unsigned, h); }

__device__ __forceinline__ float dot2(unsigned a, unsigned b, float c) {
#if __has_builtin(__builtin_amdgcn_fdot2)
    return __builtin_amdgcn_fdot2(u2h(a), u2h(b), c, false);
#else
    const half2_t x = u2h(a), y = u2h(b);
    c = fmaf((float)x[0], (float)y[0], c);
    return fmaf((float)x[1], (float)y[1], c);
#endif
}

__device__ __forceinline__ unsigned pk16(float a, float b) {
#if __has_builtin(__builtin_amdgcn_cvt_pkrtz)
    return __builtin_bit_cast(unsigned, __builtin_amdgcn_cvt_pkrtz(a, b));
#else
    const half2_t h = {(_Float16)a, (_Float16)b};
    return h2u(h);
#endif
}

// One block per (b, 15-row superstrip, 15-col segment): 36 tiles, redundancy
// 225/144 = 1.5625x (vs 1.69x for 13x13), 800 blocks (-30% fixed overhead).
// Stage: one thread owns one position's 128 channels (adjacent lanes = adjacent
// x -> coalesced; R16: breaking this quadruples HBM fetch), 2-deep register
// prefetch (T14). Band granule swizzle: uint4-granule gl of pos at ((gl+pos)&15),
// same on write and read (both-sides rule).
// NOTE: bare launch_bounds -- a min-waves clause collapses the VGPR budget and
// spills (R6: 2.6 GB scratch, R7: 58 MB scratch).
__global__ __launch_bounds__(256) void seg_fused(const float* __restrict__ f,
                                                 float* __restrict__ slots) {
    // XCD-chunked swizzle (bijective: 800 = 8*100).
    const int lb  = (blockIdx.x & 7) * (NBLK / 8) + (blockIdx.x >> 3);
    const int b   = lb / (NSST * NCS);
    const int rem = lb % (NSST * NCS);
    const int sst = rem / NCS, cs = rem % NCS;
    const int y0 = 12 * sst, xlo = 12 * cs;
    const int t = threadIdx.x;

    __shared__ unsigned band[POSN * 64];   // 57600 B: [pos][64 uints = 128 fp16]
    __shared__ float sinv[POSN];
    __shared__ unsigned sinvh[POSN];
    __shared__ uint4 Slh[16][NTIL];        // 9216 B: per-(slot, tile) S as 8 half2
    __shared__ float wmax[4];

    // ---- stage: t<225 owns position t (all 128 channels), 2-deep prefetch ----
    if (t < POSN) {
        const int r = t / SEGW, xx = t % SEGW;
        const float* gp = f + (size_t)b * NC * HW + (size_t)(y0 + r) * NW + xlo + xx;
        float ss = 0.0f;
        float vc[16], vn[16];
        #pragma unroll
        for (int k = 0; k < 16; ++k) vc[k] = gp[(size_t)k * HW];
        #pragma unroll
        for (int ch = 0; ch < 8; ++ch) {
            if (ch < 7) {
                #pragma unroll
                for (int k = 0; k < 16; ++k)
                    vn[k] = gp[(size_t)((ch + 1) * 16 + k) * HW];
            }
            #pragma unroll
            for (int k = 0; k < 16; ++k) ss = fmaf(vc[k], vc[k], ss);
            unsigned u[8];
            #pragma unroll
            for (int j = 0; j < 8; ++j) u[j] = pk16(vc[2 * j], vc[2 * j + 1]);
            *(uint4*)&band[t * 64 + (((2 * ch     + t) & 15) << 2)] =
                make_uint4(u[0], u[1], u[2], u[3]);
            *(uint4*)&band[t * 64 + (((2 * ch + 1 + t) & 15) << 2)] =
                make_uint4(u[4], u[5], u[6], u[7]);
            #pragma unroll
            for (int k = 0; k < 16; ++k) vc[k] = vn[k];
        }
        const float inv = (ss > 0.0f) ? rsqrtf(ss) : 0.0f;
        sinv[t] = inv;
        const half2_t i2 = {(_Float16)inv, (_Float16)inv};
        sinvh[t] = h2u(i2);
    }
    __syncthreads();

    // ---- S-phase: 576 items (36 tiles x 16 slots); thread t does t, t+256, t+512 ----
    #pragma unroll
    for (int jj = 0; jj < 3; ++jj) {
        const int i = t + jj * 256;
        if (i < 16 * NTIL) {
            const int tl = i >> 4, slot = i & 15;
            const int j = tl / 6, tc = tl % 6;   // strip j, tile-col tc
            half2_t s0 = u2h(0u), s1 = u2h(0u), s2 = u2h(0u), s3 = u2h(0u);
            #pragma unroll
            for (int pr = 0; pr < 5; ++pr)
                #pragma unroll
                for (int pc = 0; pc < 5; ++pc) {
                    const int pos = (2 * j + pr) * SEGW + 2 * tc + pc;
                    const uint4 v = *(const uint4*)&band[pos * 64 + (((slot + pos) & 15) << 2)];
                    const half2_t iv = u2h(sinvh[pos]);
                    s0 = u2h(v.x) * iv + s0;
                    s1 = u2h(v.y) * iv + s1;
                    s2 = u2h(v.z) * iv + s2;
                    s3 = u2h(v.w) * iv + s3;
                }
            Slh[slot][tl] = make_uint4(h2u(s0), h2u(s1), h2u(s2), h2u(s3));
        }
    }
    __syncthreads();

    // ---- dots: 900 items (36 tiles x 25 p); t<225 does 4 items at t + 225*jj ----
    float m = 0.0f;
    if (t < 225) {
        #pragma unroll
        for (int jj = 0; jj < 4; ++jj) {
            const int it = t + jj * 225;
            const int tl = it / 25, p = it % 25;
            const int j = tl / 6, tc = tl % 6;
            const int pos = (2 * j + p / 5) * SEGW + 2 * tc + (p % 5);
            float acc = 0.0f;
            #pragma unroll
            for (int slot = 0; slot < 16; ++slot) {
                const uint4 sv = Slh[slot][tl];
                const uint4 v  = *(const uint4*)&band[pos * 64 + (((slot + pos) & 15) << 2)];
                acc = dot2(v.x, sv.x, acc);
                acc = dot2(v.y, sv.y, acc);
                acc = dot2(v.z, sv.z, acc);
                acc = dot2(v.w, sv.w, acc);
            }
            m = fmaxf(m, 1.0f - acc * sinv[pos] * 0.04f);
        }
    }
    // ---- block max (m >= 0 via init 0), one slot per block ----
    #pragma unroll
    for (int off = 1; off < 64; off <<= 1) m = fmaxf(m, __shfl_xor(m, off));
    if ((t & 63) == 0) wmax[t >> 6] = m;
    __syncthreads();
    if (t == 0)
        slots[lb] = fmaxf(fmaxf(wmax[0], wmax[1]), fmaxf(wmax[2], wmax[3]));
}

// ---------------- finalize: 800 slots (25 per b) -> loss ----------------
__global__ __launch_bounds__(256) void finalize(const float* __restrict__ slots,
                                                const int* __restrict__ label,
                                                float* __restrict__ out) {
    const int t = threadIdx.x;
    __shared__ float bmax[32];
    const int b = t >> 3, k = t & 7;      // 8 lanes per b, 25 slots each
    float m = 0.0f;
    for (int i = k; i < 25; i += 8) m = fmaxf(m, slots[b * 25 + i]);
    m = fmaxf(m, __shfl_xor(m, 1));
    m = fmaxf(m, __shfl_xor(m, 2));
    m = fmaxf(m, __shfl_xor(m, 4));
    if (k == 0) bmax[b] = m;
    __syncthreads();
    if (t == 0) {
        float fs = 0.0f, rs = 0.0f, fc = 0.0f, rc = 0.0f;
        for (int b2 = 0; b2 < NB; ++b2) {
            const float tb  = bmax[b2];
            const float lbv = (float)label[b2];
            fs += tb * lbv;          fc += lbv;
            rs += tb * (1.0f - lbv); rc += (1.0f - lbv);
        }
        const float loss = 1.0f - fs / fc + rs / rc;
        out[0] = fmaxf(loss, 0.0f);
    }
}

extern "C" void kernel_launch(void* const* d_in, const int* in_sizes, int n_in,
                              void* d_out, int out_size, void* d_ws, size_t ws_size,
                              hipStream_t stream) {
    const float* feature = (const float*)d_in[0];
    const int* label     = (const int*)d_in[1];
    float* out   = (float*)d_out;
    float* slots = (float*)d_ws;   // 800 floats, fully rewritten each launch

    seg_fused<<<NBLK, 256, 0, stream>>>(feature, slots);
    finalize<<<1, 256, 0, stream>>>(slots, label, out);
}

// Round 20
// 29.250 us; speedup vs baseline: 1.1146x; 1.1146x over previous
//
#include <hip/hip_runtime.h>

// Problem constants (fixed by reference setup_inputs)
#define NB 32
#define NC 128
#define NH 63
#define NW 63
#define HW 3969          // 63*63
#define OH 30            // (63-5)/2+1
#define SEGW 13          // 13x13 block: 5 tiles x 5 strips, advance 10 in both dims
#define NROW 13
#define POSN (NROW*SEGW) // 169
#define NSST 6           // row superstrips per b (30 = 6*5)
#define NCS 6            // col segments per b (30 = 6*5)
#define NBLK (NB*NSST*NCS)  // 1152
// 63 = 6*10 + 3 and 30 = 6*5 exactly -> no edge masking anywhere.

typedef _Float16 half2_t __attribute__((ext_vector_type(2)));
__device__ __forceinline__ half2_t u2h(unsigned u) { return __builtin_bit_cast(half2_t, u); }
__device__ __forceinline__ unsigned h2u(half2_t h) { return __builtin_bit_cast(unsigned, h); }

__device__ __forceinline__ float dot2(unsigned a, unsigned b, float c) {
#if __has_builtin(__builtin_amdgcn_fdot2)
    return __builtin_amdgcn_fdot2(u2h(a), u2h(b), c, false);
#else
    const half2_t x = u2h(a), y = u2h(b);
    c = fmaf((float)x[0], (float)y[0], c);
    return fmaf((float)x[1], (float)y[1], c);
#endif
}

__device__ __forceinline__ unsigned pk16(float a, float b) {
#if __has_builtin(__builtin_amdgcn_cvt_pkrtz)
    return __builtin_bit_cast(unsigned, __builtin_amdgcn_cvt_pkrtz(a, b));
#else
    const half2_t h = {(_Float16)a, (_Float16)b};
    return h2u(h);
#endif
}

// One block per (b, 13-row superstrip, 13-col segment): 25 tiles, redundancy
// 169/100 = 1.69x; 1152 blocks at 3 blocks/CU (R19: dropping to 2/CU at 800
// blocks regresses). Stage: one thread owns one position's 128 channels
// (adjacent lanes = adjacent x -> coalesced; R16: breaking this quadruples HBM
// fetch). NEW vs R18: 32-wide stage chunks, 2-deep prefetch -> 4-batch latency
// chain instead of 8 (32 loads in flight per thread). Band granule swizzle:
// uint4-granule gl of pos at ((gl+pos)&15), same on write and read.
// NOTE: bare launch_bounds -- a min-waves clause collapses the VGPR budget and
// spills (R6: 2.6 GB scratch, R7: 58 MB scratch).
__global__ __launch_bounds__(256) void seg_fused(const float* __restrict__ f,
                                                 float* __restrict__ slots) {
    // XCD-chunked swizzle (bijective: 1152 = 8*144).
    const int lb  = (blockIdx.x & 7) * (NBLK / 8) + (blockIdx.x >> 3);
    const int b   = lb / (NSST * NCS);
    const int rem = lb % (NSST * NCS);
    const int sst = rem / NCS, cs = rem % NCS;
    const int y0 = 10 * sst, xlo = 10 * cs;
    const int t = threadIdx.x;

    __shared__ unsigned band[POSN * 64];   // 43264 B: [pos][64 uints = 128 fp16]
    __shared__ float sinv[POSN];
    __shared__ unsigned sinvh[POSN];
    __shared__ uint4 Slh[16][25];          // 6400 B: per-(slot, tile) S as 8 half2
    __shared__ float wmax[4];

    // ---- stage: t<169 owns position t; 4 chunks of 32 ch, 2-deep prefetch ----
    if (t < POSN) {
        const int r = t / SEGW, xx = t % SEGW;
        const float* gp = f + (size_t)b * NC * HW + (size_t)(y0 + r) * NW + xlo + xx;
        float ss = 0.0f;
        float vc[32], vn[32];
        #pragma unroll
        for (int k = 0; k < 32; ++k) vc[k] = gp[(size_t)k * HW];
        #pragma unroll
        for (int ch = 0; ch < 4; ++ch) {
            if (ch < 3) {
                #pragma unroll
                for (int k = 0; k < 32; ++k)
                    vn[k] = gp[(size_t)((ch + 1) * 32 + k) * HW];
            }
            #pragma unroll
            for (int k = 0; k < 32; ++k) ss = fmaf(vc[k], vc[k], ss);
            unsigned u[16];
            #pragma unroll
            for (int j = 0; j < 16; ++j) u[j] = pk16(vc[2 * j], vc[2 * j + 1]);
            #pragma unroll
            for (int q = 0; q < 4; ++q)
                *(uint4*)&band[t * 64 + (((4 * ch + q + t) & 15) << 2)] =
                    make_uint4(u[4 * q], u[4 * q + 1], u[4 * q + 2], u[4 * q + 3]);
            #pragma unroll
            for (int k = 0; k < 32; ++k) vc[k] = vn[k];
        }
        const float inv = (ss > 0.0f) ? rsqrtf(ss) : 0.0f;
        sinv[t] = inv;
        const half2_t i2 = {(_Float16)inv, (_Float16)inv};
        sinvh[t] = h2u(i2);
    }
    __syncthreads();

    // ---- S-phase: 400 items (25 tiles x 16 slots); thread t does t and t+256 ----
    #pragma unroll
    for (int jj = 0; jj < 2; ++jj) {
        const int i = t + jj * 256;
        if (i < 400) {
            const int tl = i >> 4, slot = i & 15;
            const int j = tl / 5, tc = tl % 5;   // strip j, tile-col tc
            half2_t s0 = u2h(0u), s1 = u2h(0u), s2 = u2h(0u), s3 = u2h(0u);
            #pragma unroll
            for (int pr = 0; pr < 5; ++pr)
                #pragma unroll
                for (int pc = 0; pc < 5; ++pc) {
                    const int pos = (2 * j + pr) * SEGW + 2 * tc + pc;
                    const uint4 v = *(const uint4*)&band[pos * 64 + (((slot + pos) & 15) << 2)];
                    const half2_t iv = u2h(sinvh[pos]);
                    s0 = u2h(v.x) * iv + s0;
                    s1 = u2h(v.y) * iv + s1;
                    s2 = u2h(v.z) * iv + s2;
                    s3 = u2h(v.w) * iv + s3;
                }
            Slh[slot][tl] = make_uint4(h2u(s0), h2u(s1), h2u(s2), h2u(s3));
        }
    }
    __syncthreads();

    // ---- dots: 625 items (25 tiles x 25 p); t<250 does {t, t+250} and t<125 +500 ----
    float m = 0.0f;
    #pragma unroll
    for (int jj = 0; jj < 3; ++jj) {
        const int it = t + jj * 250;
        if (t < 250 && it < 625) {
            const int tl = it / 25, p = it % 25;
            const int j = tl / 5, tc = tl % 5;
            const int pos = (2 * j + p / 5) * SEGW + 2 * tc + (p % 5);
            float acc = 0.0f;
            #pragma unroll
            for (int slot = 0; slot < 16; ++slot) {
                const uint4 sv = Slh[slot][tl];
                const uint4 v  = *(const uint4*)&band[pos * 64 + (((slot + pos) & 15) << 2)];
                acc = dot2(v.x, sv.x, acc);
                acc = dot2(v.y, sv.y, acc);
                acc = dot2(v.z, sv.z, acc);
                acc = dot2(v.w, sv.w, acc);
            }
            m = fmaxf(m, 1.0f - acc * sinv[pos] * 0.04f);
        }
    }
    // ---- block max (m >= 0 via init 0), one slot per block ----
    #pragma unroll
    for (int off = 1; off < 64; off <<= 1) m = fmaxf(m, __shfl_xor(m, off));
    if ((t & 63) == 0) wmax[t >> 6] = m;
    __syncthreads();
    if (t == 0)
        slots[lb] = fmaxf(fmaxf(wmax[0], wmax[1]), fmaxf(wmax[2], wmax[3]));
}

// ---------------- finalize: 1152 slots (36 per b) -> loss ----------------
__global__ __launch_bounds__(256) void finalize(const float* __restrict__ slots,
                                                const int* __restrict__ label,
                                                float* __restrict__ out) {
    const int t = threadIdx.x;
    __shared__ float bmax[32];
    const int b = t >> 3, k = t & 7;      // 8 lanes per b, 36 slots each
    float m = 0.0f;
    for (int i = k; i < 36; i += 8) m = fmaxf(m, slots[b * 36 + i]);
    m = fmaxf(m, __shfl_xor(m, 1));
    m = fmaxf(m, __shfl_xor(m, 2));
    m = fmaxf(m, __shfl_xor(m, 4));
    if (k == 0) bmax[b] = m;
    __syncthreads();
    if (t == 0) {
        float fs = 0.0f, rs = 0.0f, fc = 0.0f, rc = 0.0f;
        for (int b2 = 0; b2 < NB; ++b2) {
            const float tb  = bmax[b2];
            const float lbv = (float)label[b2];
            fs += tb * lbv;          fc += lbv;
            rs += tb * (1.0f - lbv); rc += (1.0f - lbv);
        }
        const float loss = 1.0f - fs / fc + rs / rc;
        out[0] = fmaxf(loss, 0.0f);
    }
}

extern "C" void kernel_launch(void* const* d_in, const int* in_sizes, int n_in,
                              void* d_out, int out_size, void* d_ws, size_t ws_size,
                              hipStream_t stream) {
    const float* feature = (const float*)d_in[0];
    const int* label     = (const int*)d_in[1];
    float* out   = (float*)d_out;
    float* slots = (float*)d_ws;   // 1152 floats, fully rewritten each launch

    seg_fused<<<NBLK, 256, 0, stream>>>(feature, slots);
    finalize<<<1, 256, 0, stream>>>(slots, label, out);
}